// Round 18
// baseline (20.904 us; speedup 1.0000x reference)
//
#include <hip/hip_runtime.h>

// TransformerBlockQuantum: B=16384, S=8, E=8, H=8 (dk=1), NW=8, FFN=512.
// R18 = R17 + (1) ALL front weights/biases staged to LDS in the pack phase;
// front matvecs read them as per-lane broadcast ds_read_b128/b32 (pipelined,
// no SGPR-limited s_load serialization). (2) post-hh __syncthreads removed:
// each wave's FFN tokens == its own front tokens (intra-wave LDS RAW is
// ordered by lgkmcnt) -> waves drift phase, MFMA overlaps front VALU.
// Structure: 256 thr (4 waves) = 256 tokens/block; f32->f16 fragment pack in
// LDS; 1-thread/token front; per-wave 4 MFMA tiles; LN2+store. 512 blocks.

typedef __fp16 half2v __attribute__((ext_vector_type(2)));
typedef __fp16 half4  __attribute__((ext_vector_type(4)));
typedef float  float4v __attribute__((ext_vector_type(4)));

#define SWZ(v, J) __int_as_float(__builtin_amdgcn_ds_swizzle(__float_as_int(v), ((J) << 5) | 0x18))
#define SWZ16(v) __int_as_float(__builtin_amdgcn_ds_swizzle(__float_as_int(v), (16 << 10) | 0x1F))
#define DOT8(a, w0, w1)                                                   \
    fmaf((a)[7], (w1).w, fmaf((a)[6], (w1).z, fmaf((a)[5], (w1).y,        \
    fmaf((a)[4], (w1).x, fmaf((a)[3], (w0).w, fmaf((a)[2], (w0).z,        \
    fmaf((a)[1], (w0).y, (a)[0] * (w0).x)))))))

// float offsets in wl[]
#define O_IPW 0
#define O_OPW 192
#define O_CW  256
#define O_IPB 320
#define O_OPB 344
#define O_CB  352
#define O_RXA 360
#define O_G1  368
#define O_B1  376
#define O_RXF 384
#define O_L2B 392
#define O_G2  400
#define O_B2  408

__global__ __launch_bounds__(256, 2) void tbq_fused(
    const float* __restrict__ x,
    const float* __restrict__ ipw, const float* __restrict__ ipb,
    const float* __restrict__ opw, const float* __restrict__ opb,
    const float* __restrict__ rxa,
    const float* __restrict__ cw,  const float* __restrict__ cb,
    const float* __restrict__ g1,  const float* __restrict__ b1,
    const float* __restrict__ rxf,
    const float* __restrict__ l1w, const float* __restrict__ l1b,
    const float* __restrict__ l2w, const float* __restrict__ l2b,
    const float* __restrict__ g2,  const float* __restrict__ b2,
    float* __restrict__ out)
{
    __shared__ half4 a1l[2048];                       // 16KB
    __shared__ half4 a2l[2048];                       // 16KB
    __shared__ __align__(16) float lds_hh[256][12];   // 12KB
    __shared__ __align__(16) float wl[416];           // 1.6KB all front weights

    const int tid = threadIdx.x;
    const int l   = tid & 63;
    const int wv  = tid >> 6;
    const int tok = blockIdx.x * 256 + tid;
    const int base = tok * 8;

    // ---- issue x load first (HBM latency overlaps pack) ----
    const float4* px = reinterpret_cast<const float4*>(x + base);
    float4 xa = px[0], xb = px[1];

    // ---- stage all front weights/biases into LDS ----
    if (tid < 192) wl[O_IPW + tid] = ipw[tid];
    else           wl[O_OPW + (tid - 192)] = opw[tid - 192];
    if (tid < 64)  wl[O_CW + tid] = cw[tid];
    if (tid < 24)  wl[O_IPB + tid] = ipb[tid];
    if (tid < 8) {
        wl[O_OPB + tid] = opb[tid]; wl[O_CB + tid]  = cb[tid];
        wl[O_RXA + tid] = rxa[tid]; wl[O_G1 + tid]  = g1[tid];
        wl[O_B1 + tid]  = b1[tid];  wl[O_RXF + tid] = rxf[tid];
        wl[O_L2B + tid] = l2b[tid]; wl[O_G2 + tid]  = g2[tid];
        wl[O_B2 + tid]  = b2[tid];
    }

    // ---- cooperative fragment pack: f32 weights -> f16 frags in LDS ----
    const half4 zh = {(__fp16)0.f, (__fp16)0.f, (__fp16)0.f, (__fp16)0.f};
    #pragma unroll 1
    for (int i = 0; i < 8; ++i) {
        const int u  = tid + i * 256;
        const int nf = u >> 6, ll = u & 63;
        const int mm = ll & 15, kk0 = (ll >> 4) * 4;
        half4 r1 = zh;
        if (ll < 32) {
            float4 w = *reinterpret_cast<const float4*>(l1w + (nf * 16 + mm) * 8 + kk0);
            half2v c0 = __builtin_amdgcn_cvt_pkrtz(w.x, w.y);
            half2v c1 = __builtin_amdgcn_cvt_pkrtz(w.z, w.w);
            r1.x = c0.x; r1.y = c0.y; r1.z = c1.x; r1.w = c1.y;
        } else if (ll < 48) {
            r1.x = (__fp16)l1b[nf * 16 + mm];
        }
        a1l[u] = r1;
        half4 r2 = zh;
        if (mm < 8) {
            float4 w = *reinterpret_cast<const float4*>(l2w + mm * 512 + nf * 16 + kk0);
            half2v c0 = __builtin_amdgcn_cvt_pkrtz(w.x, w.y);
            half2v c1 = __builtin_amdgcn_cvt_pkrtz(w.z, w.w);
            r2.x = c0.x; r2.y = c0.y; r2.z = c1.x; r2.w = c1.y;
        }
        a2l[u] = r2;
    }
    __syncthreads();   // weights + fragments visible to all

    const float4* wl4 = reinterpret_cast<const float4*>(wl);

    // ---- front: 1 thread per token; all weights from LDS ----
    float xr[8];
    xr[0] = xa.x; xr[1] = xa.y; xr[2] = xa.z; xr[3] = xa.w;
    xr[4] = xb.x; xr[5] = xb.y; xr[6] = xb.z; xr[7] = xb.w;

    float q[8], k[8], v[8];
    #pragma unroll
    for (int e = 0; e < 8; ++e) {
        float4 wq0 = wl4[e * 2],      wq1 = wl4[e * 2 + 1];
        float4 wk0 = wl4[16 + e * 2], wk1 = wl4[16 + e * 2 + 1];
        float4 wv0 = wl4[32 + e * 2], wv1 = wl4[32 + e * 2 + 1];
        q[e] = wl[O_IPB + e]      + DOT8(xr, wq0, wq1);
        k[e] = wl[O_IPB + 8 + e]  + DOT8(xr, wk0, wk1);
        v[e] = wl[O_IPB + 16 + e] + DOT8(xr, wv0, wv1);
    }

    // attention; softmax without max-subtraction; exp2 prefold
    float orow[8];
    #pragma unroll
    for (int h = 0; h < 8; ++h) {
        const float kh = k[h], vh = v[h];
        const float qh2 = q[h] * 1.44269504f;
        float kk[8], vv[8];
        kk[0] = SWZ(kh, 0); kk[1] = SWZ(kh, 1); kk[2] = SWZ(kh, 2); kk[3] = SWZ(kh, 3);
        kk[4] = SWZ(kh, 4); kk[5] = SWZ(kh, 5); kk[6] = SWZ(kh, 6); kk[7] = SWZ(kh, 7);
        vv[0] = SWZ(vh, 0); vv[1] = SWZ(vh, 1); vv[2] = SWZ(vh, 2); vv[3] = SWZ(vh, 3);
        vv[4] = SWZ(vh, 4); vv[5] = SWZ(vh, 5); vv[6] = SWZ(vh, 6); vv[7] = SWZ(vh, 7);
        float p[8];
        #pragma unroll
        for (int j = 0; j < 8; ++j) p[j] = exp2f(qh2 * kk[j]);
        float sum = ((p[0] + p[1]) + (p[2] + p[3])) + ((p[4] + p[5]) + (p[6] + p[7]));
        float ov = 0.f;
        #pragma unroll
        for (int j = 0; j < 8; ++j) ov = fmaf(p[j], vv[j], ov);
        orow[h] = ov * __builtin_amdgcn_rcpf(sum);
    }

    float ao[8];
    #pragma unroll
    for (int e = 0; e < 8; ++e) {
        float4 wo0 = wl4[48 + e * 2], wo1 = wl4[48 + e * 2 + 1];
        ao[e] = wl[O_OPB + e] + DOT8(orow, wo0, wo1);
    }

    float c[8];
    #pragma unroll
    for (int w = 0; w < 8; ++w) c[w] = __cosf(ao[w] + wl[O_RXA + w]);
    float z[8];
    {
        float run = c[0];
        #pragma unroll
        for (int w = 1; w < 8; ++w) { run *= c[w]; z[w] = run; }
        float s17 = c[1];
        #pragma unroll
        for (int w = 2; w < 8; ++w) s17 *= c[w];
        z[0] = s17;
    }

    float saq[8];
    #pragma unroll
    for (int e = 0; e < 8; ++e) {
        float4 wc0 = wl4[64 + e * 2], wc1 = wl4[64 + e * 2 + 1];
        saq[e] = ao[e] + wl[O_CB + e] + DOT8(z, wc0, wc1);
    }
    float at[8];
    #pragma unroll
    for (int e = 0; e < 8; ++e) {
        float4 wc0 = wl4[64 + e * 2], wc1 = wl4[64 + e * 2 + 1];
        at[e] = wl[O_CB + e] + DOT8(saq, wc0, wc1);
    }

    float r[8]; float mean = 0.f;
    #pragma unroll
    for (int e = 0; e < 8; ++e) { r[e] = xr[e] + at[e]; mean += r[e]; }
    mean *= 0.125f;
    float var = 0.f;
    #pragma unroll
    for (int e = 0; e < 8; ++e) { float d = r[e] - mean; var = fmaf(d, d, var); }
    var *= 0.125f;
    float rs = __builtin_amdgcn_rsqf(var + 1e-5f);
    {
        float4 hlo, hhi;
        hlo.x = fmaf((r[0] - mean) * rs, wl[O_G1 + 0], wl[O_B1 + 0]);
        hlo.y = fmaf((r[1] - mean) * rs, wl[O_G1 + 1], wl[O_B1 + 1]);
        hlo.z = fmaf((r[2] - mean) * rs, wl[O_G1 + 2], wl[O_B1 + 2]);
        hlo.w = fmaf((r[3] - mean) * rs, wl[O_G1 + 3], wl[O_B1 + 3]);
        hhi.x = fmaf((r[4] - mean) * rs, wl[O_G1 + 4], wl[O_B1 + 4]);
        hhi.y = fmaf((r[5] - mean) * rs, wl[O_G1 + 5], wl[O_B1 + 5]);
        hhi.z = fmaf((r[6] - mean) * rs, wl[O_G1 + 6], wl[O_B1 + 6]);
        hhi.w = fmaf((r[7] - mean) * rs, wl[O_G1 + 7], wl[O_B1 + 7]);
        *reinterpret_cast<float4*>(&lds_hh[tid][0]) = hlo;
        *reinterpret_cast<float4*>(&lds_hh[tid][4]) = hhi;
    }
    // NO barrier: wave wv's FFN reads only lds_hh[wv*64 .. wv*64+63] --
    // written by this same wave; lgkmcnt ordering suffices. Waves drift.

    // ---- FFN: wave wv handles its own 64 tokens = 4 tiles ----
    const int m  = l & 15;
    const int kg = (l >> 4) * 4;
    const int wtok = wv * 64;

    float4 h40 = make_float4(0.f, 0.f, 0.f, 0.f), h41 = h40, h42 = h40, h43 = h40;
    half4 bz0 = zh, bz1 = zh, bz2 = zh, bz3 = zh;
    if (l < 32) {
        h40 = *reinterpret_cast<const float4*>(&lds_hh[wtok + m][kg]);
        h41 = *reinterpret_cast<const float4*>(&lds_hh[wtok + 16 + m][kg]);
        h42 = *reinterpret_cast<const float4*>(&lds_hh[wtok + 32 + m][kg]);
        h43 = *reinterpret_cast<const float4*>(&lds_hh[wtok + 48 + m][kg]);
        float4 rx4 = *reinterpret_cast<const float4*>(&wl[O_RXF + kg]);
        half2v c0, c1;
        c0 = __builtin_amdgcn_cvt_pkrtz(__cosf(h40.x + rx4.x), __cosf(h40.y + rx4.y));
        c1 = __builtin_amdgcn_cvt_pkrtz(__cosf(h40.z + rx4.z), __cosf(h40.w + rx4.w));
        bz0.x = c0.x; bz0.y = c0.y; bz0.z = c1.x; bz0.w = c1.y;
        c0 = __builtin_amdgcn_cvt_pkrtz(__cosf(h41.x + rx4.x), __cosf(h41.y + rx4.y));
        c1 = __builtin_amdgcn_cvt_pkrtz(__cosf(h41.z + rx4.z), __cosf(h41.w + rx4.w));
        bz1.x = c0.x; bz1.y = c0.y; bz1.z = c1.x; bz1.w = c1.y;
        c0 = __builtin_amdgcn_cvt_pkrtz(__cosf(h42.x + rx4.x), __cosf(h42.y + rx4.y));
        c1 = __builtin_amdgcn_cvt_pkrtz(__cosf(h42.z + rx4.z), __cosf(h42.w + rx4.w));
        bz2.x = c0.x; bz2.y = c0.y; bz2.z = c1.x; bz2.w = c1.y;
        c0 = __builtin_amdgcn_cvt_pkrtz(__cosf(h43.x + rx4.x), __cosf(h43.y + rx4.y));
        c1 = __builtin_amdgcn_cvt_pkrtz(__cosf(h43.z + rx4.z), __cosf(h43.w + rx4.w));
        bz3.x = c0.x; bz3.y = c0.y; bz3.z = c1.x; bz3.w = c1.y;
    } else if (l < 48) {
        bz0.x = (__fp16)1.f; bz1.x = (__fp16)1.f;
        bz2.x = (__fp16)1.f; bz3.x = (__fp16)1.f;
    }

    const float4v zero4 = {0.f, 0.f, 0.f, 0.f};
    float4v acc0 = zero4, acc1 = zero4, acc2 = zero4, acc3 = zero4;
    #pragma unroll 2
    for (int nf = 0; nf < 32; ++nf) {
        half4 a1f = a1l[nf * 64 + l];
        half4 a2f = a2l[nf * 64 + l];
        float4v d0 = __builtin_amdgcn_mfma_f32_16x16x16f16(a1f, bz0, zero4, 0, 0, 0);
        float4v d1 = __builtin_amdgcn_mfma_f32_16x16x16f16(a1f, bz1, zero4, 0, 0, 0);
        float4v d2 = __builtin_amdgcn_mfma_f32_16x16x16f16(a1f, bz2, zero4, 0, 0, 0);
        float4v d3 = __builtin_amdgcn_mfma_f32_16x16x16f16(a1f, bz3, zero4, 0, 0, 0);
        half4 bu0, bu1, bu2, bu3;
        {
            half2v p0 = __builtin_amdgcn_cvt_pkrtz(d0.x, d0.y);
            half2v p1 = __builtin_amdgcn_cvt_pkrtz(d0.z, d0.w);
            bu0.x = p0.x; bu0.y = p0.y; bu0.z = p1.x; bu0.w = p1.y;
            p0 = __builtin_amdgcn_cvt_pkrtz(d1.x, d1.y);
            p1 = __builtin_amdgcn_cvt_pkrtz(d1.z, d1.w);
            bu1.x = p0.x; bu1.y = p0.y; bu1.z = p1.x; bu1.w = p1.y;
            p0 = __builtin_amdgcn_cvt_pkrtz(d2.x, d2.y);
            p1 = __builtin_amdgcn_cvt_pkrtz(d2.z, d2.w);
            bu2.x = p0.x; bu2.y = p0.y; bu2.z = p1.x; bu2.w = p1.y;
            p0 = __builtin_amdgcn_cvt_pkrtz(d3.x, d3.y);
            p1 = __builtin_amdgcn_cvt_pkrtz(d3.z, d3.w);
            bu3.x = p0.x; bu3.y = p0.y; bu3.z = p1.x; bu3.w = p1.y;
        }
        bu0 = __builtin_elementwise_max(bu0, zh);
        bu1 = __builtin_elementwise_max(bu1, zh);
        bu2 = __builtin_elementwise_max(bu2, zh);
        bu3 = __builtin_elementwise_max(bu3, zh);
        acc0 = __builtin_amdgcn_mfma_f32_16x16x16f16(a2f, bu0, acc0, 0, 0, 0);
        acc1 = __builtin_amdgcn_mfma_f32_16x16x16f16(a2f, bu1, acc1, 0, 0, 0);
        acc2 = __builtin_amdgcn_mfma_f32_16x16x16f16(a2f, bu2, acc2, 0, 0, 0);
        acc3 = __builtin_amdgcn_mfma_f32_16x16x16f16(a2f, bu3, acc3, 0, 0, 0);
    }

    // ---- epilogue: residual + LN2 + store (lanes 0-31, 4 tiles) ----
    if (l < 32) {
        const float4 lb4 = *reinterpret_cast<const float4*>(&wl[O_L2B + kg]);
        const float4 g4  = *reinterpret_cast<const float4*>(&wl[O_G2 + kg]);
        const float4 bb4 = *reinterpret_cast<const float4*>(&wl[O_B2 + kg]);
        const int obase = blockIdx.x * 256 + wtok;

        #pragma unroll
        for (int tt = 0; tt < 4; ++tt) {
            float4v acc = (tt == 0) ? acc0 : (tt == 1) ? acc1 : (tt == 2) ? acc2 : acc3;
            float4 h4   = (tt == 0) ? h40  : (tt == 1) ? h41  : (tt == 2) ? h42  : h43;
            float r2[4];
            r2[0] = h4.x + acc.x + lb4.x;
            r2[1] = h4.y + acc.y + lb4.y;
            r2[2] = h4.z + acc.z + lb4.z;
            r2[3] = h4.w + acc.w + lb4.w;
            float part = ((r2[0] + r2[1]) + (r2[2] + r2[3]));
            float mean2 = (part + SWZ16(part)) * 0.125f;
            float d0 = r2[0] - mean2, d1_ = r2[1] - mean2,
                  d2 = r2[2] - mean2, d3 = r2[3] - mean2;
            float vp = ((d0 * d0 + d1_ * d1_) + (d2 * d2 + d3 * d3));
            float rs2 = __builtin_amdgcn_rsqf((vp + SWZ16(vp)) * 0.125f + 1e-5f);
            float4 o;
            o.x = fmaf(d0 * rs2, g4.x, bb4.x);
            o.y = fmaf(d1_ * rs2, g4.y, bb4.y);
            o.z = fmaf(d2 * rs2, g4.z, bb4.z);
            o.w = fmaf(d3 * rs2, g4.w, bb4.w);
            *reinterpret_cast<float4*>(out + (obase + tt * 16 + m) * 8 + kg) = o;
        }
    }
}

extern "C" void kernel_launch(void* const* d_in, const int* in_sizes, int n_in,
                              void* d_out, int out_size, void* d_ws, size_t ws_size,
                              hipStream_t stream) {
    const float* x   = (const float*)d_in[0];
    const float* ipw = (const float*)d_in[1];
    const float* ipb = (const float*)d_in[2];
    const float* opw = (const float*)d_in[3];
    const float* opb = (const float*)d_in[4];
    const float* rxa = (const float*)d_in[5];
    const float* cw  = (const float*)d_in[6];
    const float* cb  = (const float*)d_in[7];
    const float* g1  = (const float*)d_in[8];
    const float* b1  = (const float*)d_in[9];
    const float* rxf = (const float*)d_in[10];
    const float* l1w = (const float*)d_in[11];
    const float* l1b = (const float*)d_in[12];
    const float* l2w = (const float*)d_in[13];
    const float* l2b = (const float*)d_in[14];
    const float* g2  = (const float*)d_in[15];
    const float* b2  = (const float*)d_in[16];
    float* out = (float*)d_out;

    const int tokens = 16384 * 8;               // 131072
    tbq_fused<<<dim3(tokens / 256), dim3(256), 0, stream>>>(
        x, ipw, ipb, opw, opb, rxa, cw, cb, g1, b1, rxf,
        l1w, l1b, l2w, l2b, g2, b2, out);
}